// Round 4
// baseline (312.198 us; speedup 1.0000x reference)
//
#include <hip/hip_runtime.h>
#include <hip/hip_bf16.h>
#include <cstddef>

#define BB 16
#define TT 4096
#define HH 512

typedef _Float16 half8 __attribute__((ext_vector_type(8)));
typedef float f32x4 __attribute__((ext_vector_type(4)));

// ---------------- prep ---------------------------------------------------------
// blocks 0..127 : pack Wv (f32 [n][k]) -> Bpack f16 fragment order:
//                 Bpack[TN(32)][kb(16)][lane(64)][j(8)], n=TN*16+(lane&15),
//                 k=kb*32+(lane>>4)*8+j.  Contiguous 1 KiB per wave write.
// blocks 128..191: qb[b][o] = query[b]·Wq[o] + bias[o] + conv_b[o]
// block  192     : zero ssum/ctx
__global__ void prep_kernel(const float* __restrict__ query,
                            const float* __restrict__ conv_b,
                            const float* __restrict__ Wq,
                            const float* __restrict__ Wv,
                            const float* __restrict__ bias,
                            _Float16* __restrict__ Bpack,
                            float* __restrict__ qb,
                            float* __restrict__ ssum,
                            float* __restrict__ ctx) {
    int blk = blockIdx.x;
    int tid = threadIdx.x;
    if (blk < 128) {
        int TN = blk >> 2, kq = blk & 3;
        int kb = kq * 4 + (tid >> 6);
        int lane = tid & 63;
        int n = TN * 16 + (lane & 15);
        int k = kb * 32 + ((lane >> 4) << 3);
        const float4* src = (const float4*)(Wv + (size_t)n * HH + k);
        float4 v0 = src[0], v1 = src[1];
        half8 h = { (_Float16)v0.x, (_Float16)v0.y, (_Float16)v0.z, (_Float16)v0.w,
                    (_Float16)v1.x, (_Float16)v1.y, (_Float16)v1.z, (_Float16)v1.w };
        *(half8*)(Bpack + (size_t)TN * 8192 + kb * 512 + lane * 8) = h;
    } else if (blk < 192) {
        int q = blk - 128;
        int b = q >> 2, oq = q & 3;
        __shared__ float qrow[HH];
        for (int i = tid; i < HH; i += 256) qrow[i] = query[b * HH + i];
        __syncthreads();
        int wave = tid >> 6, lane = tid & 63;
        float4 q1 = *(const float4*)(qrow + lane * 8);
        float4 q2 = *(const float4*)(qrow + lane * 8 + 4);
        for (int i = wave; i < 128; i += 4) {
            int o = oq * 128 + i;
            const float4* w = (const float4*)(Wq + (size_t)o * HH);
            float4 a = w[lane * 2], c = w[lane * 2 + 1];
            float acc = a.x * q1.x + a.y * q1.y + a.z * q1.z + a.w * q1.w
                      + c.x * q2.x + c.y * q2.y + c.z * q2.z + c.w * q2.w;
            #pragma unroll
            for (int off = 1; off < 64; off <<= 1) acc += __shfl_xor(acc, off, 64);
            if (lane == 0) qb[b * HH + o] = acc + bias[o] + conv_b[o];
        }
    } else {
        for (int i = tid; i < BB; i += 256) ssum[i] = 0.f;
        for (int i = tid; i < BB * HH; i += 256) ctx[i] = 0.f;
    }
}

// ---------------- fused GEMM + conv + tanh + score + sigmoid + context ---------
// grid 2048 = 16 b x 128 t-tiles; block 256 thr = 4 waves.
// Block tile: 32 t x 512 o (two o-passes of 256), K=512.
// Wave ng owns o in [p*256 + ng*64, +64): 2(m) x 4(n) mfma tiles per pass.
// acc = 32 VGPRs, breg dbuf = 32 -> fits 128-reg budget at 4 blocks/CU.
// As (32 KiB, xor-swizzled) staged once; doubles as value tile for context.
__global__ __launch_bounds__(256, 4) void gemm_fused_kernel(
        const float* __restrict__ value,
        const float* __restrict__ last_attn,
        const float* __restrict__ conv_w,
        const float* __restrict__ w_score,
        const float* __restrict__ b_score,
        const _Float16* __restrict__ Bpack,
        const float* __restrict__ qb,
        float* __restrict__ sbuf,
        float* __restrict__ ssum,
        float* __restrict__ ctx) {
    __shared__ _Float16 As[32 * 512];   // 32 KiB
    __shared__ float sred[32][4];
    __shared__ float s_lds[32];

    int tid = threadIdx.x;
    int blk = blockIdx.x;
    int b = blk >> 7;
    int t0 = (blk & 127) << 5;

    int lane = tid & 63, ng = tid >> 6;
    int quad = lane >> 4, lm = lane & 15;

    // ---- stage A: 32 rows x 512 f32 -> f16 LDS, xor-chunk swizzle ----
    int st = tid & 31, sg = tid >> 5;           // row, 64-col group
    const float4* pA = (const float4*)(value + ((size_t)(b * TT + t0 + st)) * HH + sg * 64);
    #pragma unroll
    for (int u = 0; u < 8; ++u) {
        float4 v0 = pA[2 * u], v1 = pA[2 * u + 1];
        int cph = (sg * 8 + u) ^ (st & 7);
        half8 h = { (_Float16)v0.x, (_Float16)v0.y, (_Float16)v0.z, (_Float16)v0.w,
                    (_Float16)v1.x, (_Float16)v1.y, (_Float16)v1.z, (_Float16)v1.w };
        *(half8*)(As + st * 512 + cph * 8) = h;
    }

    f32x4 acc[2][4];
    #pragma unroll
    for (int mt = 0; mt < 2; ++mt)
        #pragma unroll
        for (int nt = 0; nt < 4; ++nt) { f32x4 z = {0.f,0.f,0.f,0.f}; acc[mt][nt] = z; }

    half8 breg[2][4];
    float rs[2][4];
    #pragma unroll
    for (int mt = 0; mt < 2; ++mt)
        #pragma unroll
        for (int j = 0; j < 4; ++j) rs[mt][j] = 0.f;

    const _Float16* Bbase = Bpack + lane * 8;

    auto loadB = [&](half8* dst, int p, int kb) {
        #pragma unroll
        for (int nt = 0; nt < 4; ++nt)
            dst[nt] = *(const half8*)(Bbase + (size_t)(((p * 16 + ng * 4 + nt) * 16 + kb) * 512));
    };
    auto compute = [&](int kb, const half8* bb) {
        #pragma unroll
        for (int mt = 0; mt < 2; ++mt) {
            int tr = mt * 16 + lm;
            int cph = (kb * 4 + quad) ^ (tr & 7);
            half8 a = *(const half8*)(As + tr * 512 + cph * 8);
            #pragma unroll
            for (int nt = 0; nt < 4; ++nt)
                acc[mt][nt] = __builtin_amdgcn_mfma_f32_16x16x32_f16(a, bb[nt], acc[mt][nt], 0, 0, 0);
        }
    };
    auto epi = [&](int p) {
        float qvv[4], c0v[4], c1v[4], c2v[4], wvv[4];
        #pragma unroll
        for (int nt = 0; nt < 4; ++nt) {
            int o = p * 256 + ng * 64 + nt * 16 + lm;
            qvv[nt] = qb[b * HH + o];
            c0v[nt] = conv_w[o * 3 + 0];
            c1v[nt] = conv_w[o * 3 + 1];
            c2v[nt] = conv_w[o * 3 + 2];
            wvv[nt] = w_score[o];
        }
        #pragma unroll
        for (int mt = 0; mt < 2; ++mt) {
            #pragma unroll
            for (int j = 0; j < 4; ++j) {
                int tg = t0 + mt * 16 + quad * 4 + j;
                const float* la = last_attn + b * TT + tg;
                float lam = (tg > 0) ? la[-1] : 0.f;
                float la0 = la[0];
                float lap = (tg < TT - 1) ? la[1] : 0.f;
                float r = 0.f;
                #pragma unroll
                for (int nt = 0; nt < 4; ++nt) {
                    float act = acc[mt][nt][j] + qvv[nt]
                              + c0v[nt] * lam + c1v[nt] * la0 + c2v[nt] * lap;
                    act = fminf(15.f, fmaxf(-15.f, act));
                    float e2 = __expf(2.f * act);
                    r += ((e2 - 1.f) / (e2 + 1.f)) * wvv[nt];
                }
                rs[mt][j] += r;
            }
        }
    };

    loadB(breg[0], 0, 0);
    __syncthreads();

    // ---- pass 0 ----
    #pragma unroll
    for (int kb = 0; kb < 16; ++kb) {
        if (kb < 15) loadB(breg[(kb + 1) & 1], 0, kb + 1);
        else         loadB(breg[0], 1, 0);          // prefetch pass-1 kb0
        compute(kb, breg[kb & 1]);
    }
    epi(0);
    #pragma unroll
    for (int mt = 0; mt < 2; ++mt)
        #pragma unroll
        for (int nt = 0; nt < 4; ++nt) { f32x4 z = {0.f,0.f,0.f,0.f}; acc[mt][nt] = z; }

    // ---- pass 1 ----
    #pragma unroll
    for (int kb = 0; kb < 16; ++kb) {
        if (kb < 15) loadB(breg[(kb + 1) & 1], 1, kb + 1);
        compute(kb, breg[kb & 1]);
    }
    epi(1);

    // ---- score reduce, sigmoid ----
    #pragma unroll
    for (int mt = 0; mt < 2; ++mt)
        #pragma unroll
        for (int j = 0; j < 4; ++j) {
            float v = rs[mt][j];
            #pragma unroll
            for (int off = 1; off < 16; off <<= 1) v += __shfl_xor(v, off, 64);
            if (lm == 0) sred[mt * 16 + quad * 4 + j][ng] = v;
        }
    __syncthreads();
    if (tid < 32) {
        float sc = b_score[0] + sred[tid][0] + sred[tid][1] + sred[tid][2] + sred[tid][3];
        float s = 1.f / (1.f + __expf(-sc));
        s_lds[tid] = s;
        sbuf[b * TT + t0 + tid] = s;
        float tot = s;
        #pragma unroll
        for (int off = 1; off < 32; off <<= 1) tot += __shfl_xor(tot, off, 64);
        if (tid == 0) atomicAdd(&ssum[b], tot);
    }
    __syncthreads();

    // ---- context partial from resident f16 tile ----
    #pragma unroll
    for (int hh = 0; hh < 2; ++hh) {
        int h = tid + hh * 256;
        int cl = h >> 3, j = h & 7;
        float a = 0.f;
        #pragma unroll 8
        for (int t2 = 0; t2 < 32; ++t2) {
            int cph = cl ^ (t2 & 7);
            a += s_lds[t2] * (float)As[t2 * 512 + cph * 8 + j];
        }
        atomicAdd(&ctx[b * HH + h], a);
    }
}

// ---------------- finalize: out = [ctx/ssum, query] ++ attn = s/ssum -----------
__global__ void finalize_kernel(const float* __restrict__ query,
                                const float* __restrict__ ctx,
                                const float* __restrict__ sbuf,
                                const float* __restrict__ ssum,
                                float* __restrict__ out) {
    int idx = blockIdx.x * 256 + threadIdx.x;
    if (idx < BB * 2 * HH) {
        int b = idx >> 10, c = idx & 1023;
        float v;
        if (c < HH) v = ctx[b * HH + c] / ssum[b];
        else        v = query[b * HH + (c - HH)];
        out[idx] = v;
    } else {
        int j = idx - BB * 2 * HH;
        int b = j >> 12, t = j & 4095;
        out[idx] = sbuf[b * TT + t] / ssum[b];
    }
}

extern "C" void kernel_launch(void* const* d_in, const int* in_sizes, int n_in,
                              void* d_out, int out_size, void* d_ws, size_t ws_size,
                              hipStream_t stream) {
    const float* query     = (const float*)d_in[0];
    const float* value     = (const float*)d_in[1];
    const float* last_attn = (const float*)d_in[2];
    const float* conv_w    = (const float*)d_in[3];
    const float* conv_b    = (const float*)d_in[4];
    const float* Wq        = (const float*)d_in[5];
    const float* Wv        = (const float*)d_in[6];
    const float* bias      = (const float*)d_in[7];
    const float* w_score   = (const float*)d_in[8];
    const float* b_score   = (const float*)d_in[9];

    char* ws = (char*)d_ws;
    _Float16* Bpack = (_Float16*)ws;           // 524288 B
    float* qb     = (float*)(ws + 524288);     // 32768 B
    float* sbuf   = (float*)(ws + 557056);     // 262144 B
    float* ssum   = (float*)(ws + 819200);     // 64 B
    float* ctx    = (float*)(ws + 819264);     // 32768 B
    float* out    = (float*)d_out;

    prep_kernel<<<193, 256, 0, stream>>>(query, conv_b, Wq, Wv, bias, Bpack, qb, ssum, ctx);
    gemm_fused_kernel<<<2048, 256, 0, stream>>>(value, last_attn, conv_w, w_score,
                                                b_score, Bpack, qb, sbuf, ssum, ctx);
    finalize_kernel<<<320, 256, 0, stream>>>(query, ctx, sbuf, ssum, out);
}

// Round 5
// 279.635 us; speedup vs baseline: 1.1164x; 1.1164x over previous
//
#include <hip/hip_runtime.h>
#include <hip/hip_bf16.h>
#include <cstddef>

#define BB 16
#define TT 4096
#define HH 512

typedef _Float16 half8 __attribute__((ext_vector_type(8)));
typedef float f32x4 __attribute__((ext_vector_type(4)));

// ---------------- prep ---------------------------------------------------------
// blocks 0..127 : pack Wv (f32 [n][k]) -> Bpack f16, layout [kb(16)][tn(32)][lane(64)][8]
//                 n = tn*16 + (lane&15), k = kb*32 + (lane>>4)*8 + j.
//                 A wave's 4 consecutive n-tiles at one kb = contiguous 4 KiB.
// blocks 128..191: qb[b][o] = query[b]·Wq[o] + bias[o] + conv_b[o]
// block  192     : zero ssum/ctx
__global__ void prep_kernel(const float* __restrict__ query,
                            const float* __restrict__ conv_b,
                            const float* __restrict__ Wq,
                            const float* __restrict__ Wv,
                            const float* __restrict__ bias,
                            _Float16* __restrict__ Bpack,
                            float* __restrict__ qb,
                            float* __restrict__ ssum,
                            float* __restrict__ ctx) {
    int blk = blockIdx.x;
    int tid = threadIdx.x;
    if (blk < 128) {
        int tn = blk >> 2, kq = blk & 3;
        int kb = kq * 4 + (tid >> 6);
        int lane = tid & 63;
        int n = tn * 16 + (lane & 15);
        int k = kb * 32 + ((lane >> 4) << 3);
        const float4* src = (const float4*)(Wv + (size_t)n * HH + k);
        float4 v0 = src[0], v1 = src[1];
        half8 h = { (_Float16)v0.x, (_Float16)v0.y, (_Float16)v0.z, (_Float16)v0.w,
                    (_Float16)v1.x, (_Float16)v1.y, (_Float16)v1.z, (_Float16)v1.w };
        *(half8*)(Bpack + ((size_t)(kb * 32 + tn) * 64 + lane) * 8) = h;
    } else if (blk < 192) {
        int q = blk - 128;
        int b = q >> 2, oq = q & 3;
        __shared__ float qrow[HH];
        for (int i = tid; i < HH; i += 256) qrow[i] = query[b * HH + i];
        __syncthreads();
        int wave = tid >> 6, lane = tid & 63;
        float4 q1 = *(const float4*)(qrow + lane * 8);
        float4 q2 = *(const float4*)(qrow + lane * 8 + 4);
        for (int i = wave; i < 128; i += 4) {
            int o = oq * 128 + i;
            const float4* w = (const float4*)(Wq + (size_t)o * HH);
            float4 a = w[lane * 2], c = w[lane * 2 + 1];
            float acc = a.x * q1.x + a.y * q1.y + a.z * q1.z + a.w * q1.w
                      + c.x * q2.x + c.y * q2.y + c.z * q2.z + c.w * q2.w;
            #pragma unroll
            for (int off = 1; off < 64; off <<= 1) acc += __shfl_xor(acc, off, 64);
            if (lane == 0) qb[b * HH + o] = acc + bias[o] + conv_b[o];
        }
    } else {
        for (int i = tid; i < BB; i += 256) ssum[i] = 0.f;
        for (int i = tid; i < BB * HH; i += 256) ctx[i] = 0.f;
    }
}

// ---------------- fused GEMM + conv + tanh + score + sigmoid + context ---------
// grid 1024 = 16 b x 64 t-tiles; block 512 thr = 8 waves.
// Block tile: 64 t x 512 o, K=512, two o-passes of 256.
// Wave w: msub=w&1 (32-row half), ng=w>>1 (64-col slice of the pass).
// acc = 2x4 tiles = 32 regs; B double-buffered via ONE running pointer with
// imm-offset nt loads (no address blowup -> no spill).
// As staged once (xor-swizzled); K-loop is barrier-free; tile doubles as the
// value data for the fused context reduction.
__global__ __launch_bounds__(512, 4) void gemm_fused_kernel(
        const float* __restrict__ value,
        const float* __restrict__ last_attn,
        const float* __restrict__ conv_w,
        const float* __restrict__ w_score,
        const float* __restrict__ b_score,
        const _Float16* __restrict__ Bpack,
        const float* __restrict__ qb,
        float* __restrict__ sbuf,
        float* __restrict__ ssum,
        float* __restrict__ ctx) {
    __shared__ _Float16 As[64 * 512];   // 64 KiB
    __shared__ float sred[64][4];
    __shared__ float s_lds[64];

    int tid = threadIdx.x;
    int blk = blockIdx.x;
    int b = blk >> 6;
    int t0 = (blk & 63) << 5;
    t0 <<= 1;                            // (blk&63)*64

    int lane = tid & 63;
    int w = tid >> 6, msub = w & 1, ng = w >> 1;
    int quad = lane >> 4, lm = lane & 15;

    // ---- stage A: 64 rows x 512 f32 -> f16 LDS, xor-chunk swizzle, once ----
    {
        int st = tid >> 3, cc = tid & 7;
        const float4* pA = (const float4*)(value + ((size_t)(b * TT + t0 + st)) * HH) + cc * 2;
        #pragma unroll
        for (int u = 0; u < 8; ++u) {
            float4 v0 = pA[u * 16], v1 = pA[u * 16 + 1];
            int cph = (cc + u * 8) ^ (st & 7);
            half8 h = { (_Float16)v0.x, (_Float16)v0.y, (_Float16)v0.z, (_Float16)v0.w,
                        (_Float16)v1.x, (_Float16)v1.y, (_Float16)v1.z, (_Float16)v1.w };
            *(half8*)(As + st * 512 + cph * 8) = h;
        }
    }

    float rs[2][4];
    #pragma unroll
    for (int mt = 0; mt < 2; ++mt)
        #pragma unroll
        for (int j = 0; j < 4; ++j) rs[mt][j] = 0.f;

    __syncthreads();

    #pragma unroll 1
    for (int p = 0; p < 2; ++p) {
        f32x4 acc[2][4];
        #pragma unroll
        for (int mt = 0; mt < 2; ++mt)
            #pragma unroll
            for (int nt = 0; nt < 4; ++nt) { f32x4 z = {0.f,0.f,0.f,0.f}; acc[mt][nt] = z; }

        // running B pointer: fragments for (kb, ng*4 + nt) -- nt at imm offsets
        const _Float16* bp = Bpack + (size_t)(p * 16 + ng * 4) * 512 + lane * 8;
        half8 breg[2][4];
        #pragma unroll
        for (int nt = 0; nt < 4; ++nt)
            breg[0][nt] = *(const half8*)(bp + nt * 512);
        bp += 16384;

        #pragma unroll 2
        for (int kb = 0; kb < 16; ++kb) {
            int cb = kb & 1;
            if (kb < 15) {
                #pragma unroll
                for (int nt = 0; nt < 4; ++nt)
                    breg[cb ^ 1][nt] = *(const half8*)(bp + nt * 512);
                bp += 16384;
            }
            #pragma unroll
            for (int mt = 0; mt < 2; ++mt) {
                int tr = msub * 32 + mt * 16 + lm;
                int cph = ((kb << 2) + quad) ^ (tr & 7);
                half8 a = *(const half8*)(As + tr * 512 + cph * 8);
                #pragma unroll
                for (int nt = 0; nt < 4; ++nt)
                    acc[mt][nt] = __builtin_amdgcn_mfma_f32_16x16x32_f16(a, breg[cb][nt], acc[mt][nt], 0, 0, 0);
            }
        }

        // epilogue partial: conv + tanh + w_score dot, accumulate into rs
        #pragma unroll
        for (int nt = 0; nt < 4; ++nt) {
            int o = p * 256 + ng * 64 + nt * 16 + lm;
            float qv = qb[b * HH + o];
            float c0 = conv_w[o * 3 + 0];
            float c1 = conv_w[o * 3 + 1];
            float c2 = conv_w[o * 3 + 2];
            float wv = w_score[o];
            #pragma unroll
            for (int mt = 0; mt < 2; ++mt) {
                #pragma unroll
                for (int j = 0; j < 4; ++j) {
                    int tg = t0 + msub * 32 + mt * 16 + quad * 4 + j;
                    const float* la = last_attn + b * TT + tg;
                    float lam = (tg > 0) ? la[-1] : 0.f;
                    float la0 = la[0];
                    float lap = (tg < TT - 1) ? la[1] : 0.f;
                    float act = acc[mt][nt][j] + qv + c0 * lam + c1 * la0 + c2 * lap;
                    act = fminf(15.f, fmaxf(-15.f, act));
                    float e2 = __expf(2.f * act);
                    rs[mt][j] += ((e2 - 1.f) / (e2 + 1.f)) * wv;
                }
            }
        }
    }

    // ---- score reduce across lanes/waves, sigmoid ----
    #pragma unroll
    for (int mt = 0; mt < 2; ++mt)
        #pragma unroll
        for (int j = 0; j < 4; ++j) {
            float v = rs[mt][j];
            #pragma unroll
            for (int off = 1; off < 16; off <<= 1) v += __shfl_xor(v, off, 64);
            if (lm == 0) {
                if (ng == 0) sred[msub * 32 + mt * 16 + quad * 4 + j][0] = v;
            }
        }
    __syncthreads();
    #pragma unroll
    for (int mt = 0; mt < 2; ++mt)
        #pragma unroll
        for (int j = 0; j < 4; ++j) {
            float v = rs[mt][j];
            #pragma unroll
            for (int off = 1; off < 16; off <<= 1) v += __shfl_xor(v, off, 64);
            if (lm == 0 && ng != 0)
                atomicAdd(&sred[msub * 32 + mt * 16 + quad * 4 + j][0], v);
        }
    __syncthreads();

    if (tid < 64) {
        float sc = b_score[0] + sred[tid][0];
        float s = 1.f / (1.f + __expf(-sc));
        s_lds[tid] = s;
        sbuf[b * TT + t0 + tid] = s;
        float tot = s;
        #pragma unroll
        for (int off = 1; off < 64; off <<= 1) tot += __shfl_xor(tot, off, 64);
        if (tid == 0) atomicAdd(&ssum[b], tot);
    }
    __syncthreads();

    // ---- context partial from resident f16 tile: one column per thread ----
    {
        int h = tid;
        int cl = h >> 3, j = h & 7;
        float a = 0.f;
        #pragma unroll 8
        for (int t2 = 0; t2 < 64; ++t2) {
            int cph = cl ^ (t2 & 7);
            a += s_lds[t2] * (float)As[t2 * 512 + cph * 8 + j];
        }
        atomicAdd(&ctx[b * HH + h], a);
    }
}

// ---------------- finalize: out = [ctx/ssum, query] ++ attn = s/ssum -----------
__global__ void finalize_kernel(const float* __restrict__ query,
                                const float* __restrict__ ctx,
                                const float* __restrict__ sbuf,
                                const float* __restrict__ ssum,
                                float* __restrict__ out) {
    int idx = blockIdx.x * 256 + threadIdx.x;
    if (idx < BB * 2 * HH) {
        int b = idx >> 10, c = idx & 1023;
        float v;
        if (c < HH) v = ctx[b * HH + c] / ssum[b];
        else        v = query[b * HH + (c - HH)];
        out[idx] = v;
    } else {
        int j = idx - BB * 2 * HH;
        int b = j >> 12, t = j & 4095;
        out[idx] = sbuf[b * TT + t] / ssum[b];
    }
}

extern "C" void kernel_launch(void* const* d_in, const int* in_sizes, int n_in,
                              void* d_out, int out_size, void* d_ws, size_t ws_size,
                              hipStream_t stream) {
    const float* query     = (const float*)d_in[0];
    const float* value     = (const float*)d_in[1];
    const float* last_attn = (const float*)d_in[2];
    const float* conv_w    = (const float*)d_in[3];
    const float* conv_b    = (const float*)d_in[4];
    const float* Wq        = (const float*)d_in[5];
    const float* Wv        = (const float*)d_in[6];
    const float* bias      = (const float*)d_in[7];
    const float* w_score   = (const float*)d_in[8];
    const float* b_score   = (const float*)d_in[9];

    char* ws = (char*)d_ws;
    _Float16* Bpack = (_Float16*)ws;           // 524288 B
    float* qb     = (float*)(ws + 524288);     // 32768 B
    float* sbuf   = (float*)(ws + 557056);     // 262144 B
    float* ssum   = (float*)(ws + 819200);     // 64 B
    float* ctx    = (float*)(ws + 819264);     // 32768 B
    float* out    = (float*)d_out;

    prep_kernel<<<193, 256, 0, stream>>>(query, conv_b, Wq, Wv, bias, Bpack, qb, ssum, ctx);
    gemm_fused_kernel<<<1024, 512, 0, stream>>>(value, last_attn, conv_w, w_score,
                                                b_score, Bpack, qb, sbuf, ssum, ctx);
    finalize_kernel<<<320, 256, 0, stream>>>(query, ctx, sbuf, ssum, out);
}

// Round 6
// 265.901 us; speedup vs baseline: 1.1741x; 1.0517x over previous
//
#include <hip/hip_runtime.h>
#include <hip/hip_bf16.h>
#include <cstddef>

#define BB 16
#define TT 4096
#define HH 512

typedef _Float16 half8 __attribute__((ext_vector_type(8)));
typedef float f32x4 __attribute__((ext_vector_type(4)));

__device__ __forceinline__ float fast_rcp(float x) { return __builtin_amdgcn_rcpf(x); }

// ---------------- prep ---------------------------------------------------------
// blocks 0..127 : pack Wv (f32 [n][k]) -> Bpack f16, layout [kb(16)][tn(32)][lane(64)][8]
//                 n = tn*16 + (lane&15), k = kb*32 + (lane>>4)*8 + j.
//                 A wave's 4 consecutive n-tiles at one kb = contiguous 4 KiB.
// blocks 128..191: qb[b][o] = query[b]·Wq[o] + bias[o] + conv_b[o]
// block  192     : zero ssum/ctx
__global__ void prep_kernel(const float* __restrict__ query,
                            const float* __restrict__ conv_b,
                            const float* __restrict__ Wq,
                            const float* __restrict__ Wv,
                            const float* __restrict__ bias,
                            _Float16* __restrict__ Bpack,
                            float* __restrict__ qb,
                            float* __restrict__ ssum,
                            float* __restrict__ ctx) {
    int blk = blockIdx.x;
    int tid = threadIdx.x;
    if (blk < 128) {
        int tn = blk >> 2, kq = blk & 3;
        int kb = kq * 4 + (tid >> 6);
        int lane = tid & 63;
        int n = tn * 16 + (lane & 15);
        int k = kb * 32 + ((lane >> 4) << 3);
        const float4* src = (const float4*)(Wv + (size_t)n * HH + k);
        float4 v0 = src[0], v1 = src[1];
        half8 h = { (_Float16)v0.x, (_Float16)v0.y, (_Float16)v0.z, (_Float16)v0.w,
                    (_Float16)v1.x, (_Float16)v1.y, (_Float16)v1.z, (_Float16)v1.w };
        *(half8*)(Bpack + ((size_t)(kb * 32 + tn) * 64 + lane) * 8) = h;
    } else if (blk < 192) {
        int q = blk - 128;
        int b = q >> 2, oq = q & 3;
        __shared__ float qrow[HH];
        for (int i = tid; i < HH; i += 256) qrow[i] = query[b * HH + i];
        __syncthreads();
        int wave = tid >> 6, lane = tid & 63;
        float4 q1 = *(const float4*)(qrow + lane * 8);
        float4 q2 = *(const float4*)(qrow + lane * 8 + 4);
        for (int i = wave; i < 128; i += 4) {
            int o = oq * 128 + i;
            const float4* w = (const float4*)(Wq + (size_t)o * HH);
            float4 a = w[lane * 2], c = w[lane * 2 + 1];
            float acc = a.x * q1.x + a.y * q1.y + a.z * q1.z + a.w * q1.w
                      + c.x * q2.x + c.y * q2.y + c.z * q2.z + c.w * q2.w;
            #pragma unroll
            for (int off = 1; off < 64; off <<= 1) acc += __shfl_xor(acc, off, 64);
            if (lane == 0) qb[b * HH + o] = acc + bias[o] + conv_b[o];
        }
    } else {
        for (int i = tid; i < BB; i += 256) ssum[i] = 0.f;
        for (int i = tid; i < BB * HH; i += 256) ctx[i] = 0.f;
    }
}

// ---------------- fused GEMM + conv + tanh + score + sigmoid + context ---------
// grid 1024 = 16 b x 64 t-tiles; block 512 thr = 8 waves.
// Block tile: 64 t x 512 o, K=512, SINGLE pass.
// Wave ng (0..7): all 64 rows x 64 cols [ng*64, ng*64+64): 4(mt) x 4(nt) tiles.
// acc = 64 regs (AGPR); B per wave = 64 KB -> block B traffic = 1x Bpack.
// B double-buffered via one running pointer, nt at imm offsets (no spill).
// As staged once (xor-swizzled); K-loop barrier-free; tile reused for context.
__global__ __launch_bounds__(512, 4) void gemm_fused_kernel(
        const float* __restrict__ value,
        const float* __restrict__ last_attn,
        const float* __restrict__ conv_w,
        const float* __restrict__ w_score,
        const float* __restrict__ b_score,
        const _Float16* __restrict__ Bpack,
        const float* __restrict__ qb,
        float* __restrict__ sbuf,
        float* __restrict__ ssum,
        float* __restrict__ ctx) {
    __shared__ _Float16 As[64 * 512];   // 64 KiB
    __shared__ float sred[64][8];
    __shared__ float s_lds[64];

    int tid = threadIdx.x;
    int blk = blockIdx.x;
    int b = blk >> 6;
    int t0 = (blk & 63) << 6;

    int lane = tid & 63, ng = tid >> 6;
    int quad = lane >> 4, lm = lane & 15;

    // ---- stage A: 64 rows x 512 f32 -> f16 LDS, xor-chunk swizzle, once ----
    {
        int st = tid >> 3, cc = tid & 7;
        const float4* pA = (const float4*)(value + ((size_t)(b * TT + t0 + st)) * HH) + cc * 2;
        #pragma unroll
        for (int u = 0; u < 8; ++u) {
            float4 v0 = pA[u * 16], v1 = pA[u * 16 + 1];
            int cph = (cc + u * 8) ^ (st & 7);
            half8 h = { (_Float16)v0.x, (_Float16)v0.y, (_Float16)v0.z, (_Float16)v0.w,
                        (_Float16)v1.x, (_Float16)v1.y, (_Float16)v1.z, (_Float16)v1.w };
            *(half8*)(As + st * 512 + cph * 8) = h;
        }
    }

    f32x4 acc[4][4];
    #pragma unroll
    for (int mt = 0; mt < 4; ++mt)
        #pragma unroll
        for (int nt = 0; nt < 4; ++nt) { f32x4 z = {0.f,0.f,0.f,0.f}; acc[mt][nt] = z; }

    // running B pointer: fragments for (kb, ng*4 + nt) -- nt at imm offsets
    const _Float16* bp = Bpack + (size_t)(ng * 4) * 512 + lane * 8;
    half8 breg[2][4];
    #pragma unroll
    for (int nt = 0; nt < 4; ++nt)
        breg[0][nt] = *(const half8*)(bp + nt * 512);
    bp += 16384;

    __syncthreads();

    #pragma unroll 2
    for (int kb = 0; kb < 16; ++kb) {
        int cb = kb & 1;
        if (kb < 15) {
            #pragma unroll
            for (int nt = 0; nt < 4; ++nt)
                breg[cb ^ 1][nt] = *(const half8*)(bp + nt * 512);
            bp += 16384;
        }
        #pragma unroll
        for (int mt = 0; mt < 4; ++mt) {
            int tr = mt * 16 + lm;
            int cph = ((kb << 2) + quad) ^ (tr & 7);
            half8 a = *(const half8*)(As + tr * 512 + cph * 8);
            #pragma unroll
            for (int nt = 0; nt < 4; ++nt)
                acc[mt][nt] = __builtin_amdgcn_mfma_f32_16x16x32_f16(a, breg[cb][nt], acc[mt][nt], 0, 0, 0);
        }
    }

    // ---- epilogue: conv + tanh + w_score dot ----
    float qvv[4], c0v[4], c1v[4], c2v[4], wvv[4];
    #pragma unroll
    for (int nt = 0; nt < 4; ++nt) {
        int o = ng * 64 + nt * 16 + lm;
        qvv[nt] = qb[b * HH + o];
        c0v[nt] = conv_w[o * 3 + 0];
        c1v[nt] = conv_w[o * 3 + 1];
        c2v[nt] = conv_w[o * 3 + 2];
        wvv[nt] = w_score[o];
    }
    float rs[4][4];
    #pragma unroll
    for (int mt = 0; mt < 4; ++mt) {
        #pragma unroll
        for (int j = 0; j < 4; ++j) {
            int tg = t0 + mt * 16 + quad * 4 + j;
            const float* la = last_attn + b * TT + tg;
            float lam = (tg > 0) ? la[-1] : 0.f;
            float la0 = la[0];
            float lap = (tg < TT - 1) ? la[1] : 0.f;
            float r = 0.f;
            #pragma unroll
            for (int nt = 0; nt < 4; ++nt) {
                float act = acc[mt][nt][j] + qvv[nt]
                          + c0v[nt] * lam + c1v[nt] * la0 + c2v[nt] * lap;
                act = fminf(15.f, fmaxf(-15.f, act));
                float e2 = __expf(2.f * act);
                // tanh = 1 - 2/(e2+1)
                r += (1.f - 2.f * fast_rcp(e2 + 1.f)) * wvv[nt];
            }
            rs[mt][j] = r;
        }
    }

    // ---- score reduce across lanes (16 col-lanes), then waves, sigmoid ----
    #pragma unroll
    for (int mt = 0; mt < 4; ++mt)
        #pragma unroll
        for (int j = 0; j < 4; ++j) {
            float v = rs[mt][j];
            #pragma unroll
            for (int off = 1; off < 16; off <<= 1) v += __shfl_xor(v, off, 64);
            if (lm == 0) sred[mt * 16 + quad * 4 + j][ng] = v;
        }
    __syncthreads();

    if (tid < 64) {
        float sc = b_score[0];
        #pragma unroll
        for (int k = 0; k < 8; ++k) sc += sred[tid][k];
        float s = fast_rcp(1.f + __expf(-sc));
        s_lds[tid] = s;
        sbuf[b * TT + t0 + tid] = s;
        float tot = s;
        #pragma unroll
        for (int off = 1; off < 64; off <<= 1) tot += __shfl_xor(tot, off, 64);
        if (tid == 0) atomicAdd(&ssum[b], tot);
    }
    __syncthreads();

    // ---- context partial from resident f16 tile: one column per thread ----
    {
        int h = tid;
        int cl = h >> 3, j = h & 7;
        float a = 0.f;
        #pragma unroll 8
        for (int t2 = 0; t2 < 64; ++t2) {
            int cph = cl ^ (t2 & 7);
            a += s_lds[t2] * (float)As[t2 * 512 + cph * 8 + j];
        }
        atomicAdd(&ctx[b * HH + h], a);
    }
}

// ---------------- finalize: out = [ctx/ssum, query] ++ attn = s/ssum -----------
__global__ void finalize_kernel(const float* __restrict__ query,
                                const float* __restrict__ ctx,
                                const float* __restrict__ sbuf,
                                const float* __restrict__ ssum,
                                float* __restrict__ out) {
    int idx = blockIdx.x * 256 + threadIdx.x;
    if (idx < BB * 2 * HH) {
        int b = idx >> 10, c = idx & 1023;
        float v;
        if (c < HH) v = ctx[b * HH + c] / ssum[b];
        else        v = query[b * HH + (c - HH)];
        out[idx] = v;
    } else {
        int j = idx - BB * 2 * HH;
        int b = j >> 12, t = j & 4095;
        out[idx] = sbuf[b * TT + t] / ssum[b];
    }
}

extern "C" void kernel_launch(void* const* d_in, const int* in_sizes, int n_in,
                              void* d_out, int out_size, void* d_ws, size_t ws_size,
                              hipStream_t stream) {
    const float* query     = (const float*)d_in[0];
    const float* value     = (const float*)d_in[1];
    const float* last_attn = (const float*)d_in[2];
    const float* conv_w    = (const float*)d_in[3];
    const float* conv_b    = (const float*)d_in[4];
    const float* Wq        = (const float*)d_in[5];
    const float* Wv        = (const float*)d_in[6];
    const float* bias      = (const float*)d_in[7];
    const float* w_score   = (const float*)d_in[8];
    const float* b_score   = (const float*)d_in[9];

    char* ws = (char*)d_ws;
    _Float16* Bpack = (_Float16*)ws;           // 524288 B
    float* qb     = (float*)(ws + 524288);     // 32768 B
    float* sbuf   = (float*)(ws + 557056);     // 262144 B
    float* ssum   = (float*)(ws + 819200);     // 64 B
    float* ctx    = (float*)(ws + 819264);     // 32768 B
    float* out    = (float*)d_out;

    prep_kernel<<<193, 256, 0, stream>>>(query, conv_b, Wq, Wv, bias, Bpack, qb, ssum, ctx);
    gemm_fused_kernel<<<1024, 512, 0, stream>>>(value, last_attn, conv_w, w_score,
                                                b_score, Bpack, qb, sbuf, ssum, ctx);
    finalize_kernel<<<320, 256, 0, stream>>>(query, ctx, sbuf, ssum, out);
}

// Round 7
// 259.904 us; speedup vs baseline: 1.2012x; 1.0231x over previous
//
#include <hip/hip_runtime.h>
#include <hip/hip_bf16.h>
#include <cstddef>

#define BB 16
#define TT 4096
#define HH 512

typedef _Float16 half8 __attribute__((ext_vector_type(8)));
typedef float f32x4 __attribute__((ext_vector_type(4)));

__device__ __forceinline__ float fast_rcp(float x) { return __builtin_amdgcn_rcpf(x); }

// ---------------- prep ---------------------------------------------------------
// blocks 0..127 : pack Wv (f32 [n][k]) -> Bpack f16, layout [kb(16)][tn(32)][lane(64)][8]
//                 n = tn*16 + (lane&15), k = kb*32 + (lane>>4)*8 + j.
// blocks 128..191: qb[b][o] = query[b]·Wq[o] + bias[o] + conv_b[o]
// block  192     : zero ssum/ctx
__global__ void prep_kernel(const float* __restrict__ query,
                            const float* __restrict__ conv_b,
                            const float* __restrict__ Wq,
                            const float* __restrict__ Wv,
                            const float* __restrict__ bias,
                            _Float16* __restrict__ Bpack,
                            float* __restrict__ qb,
                            float* __restrict__ ssum,
                            float* __restrict__ ctx) {
    int blk = blockIdx.x;
    int tid = threadIdx.x;
    if (blk < 128) {
        int tn = blk >> 2, kq = blk & 3;
        int kb = kq * 4 + (tid >> 6);
        int lane = tid & 63;
        int n = tn * 16 + (lane & 15);
        int k = kb * 32 + ((lane >> 4) << 3);
        const float4* src = (const float4*)(Wv + (size_t)n * HH + k);
        float4 v0 = src[0], v1 = src[1];
        half8 h = { (_Float16)v0.x, (_Float16)v0.y, (_Float16)v0.z, (_Float16)v0.w,
                    (_Float16)v1.x, (_Float16)v1.y, (_Float16)v1.z, (_Float16)v1.w };
        *(half8*)(Bpack + ((size_t)(kb * 32 + tn) * 64 + lane) * 8) = h;
    } else if (blk < 192) {
        int q = blk - 128;
        int b = q >> 2, oq = q & 3;
        __shared__ float qrow[HH];
        for (int i = tid; i < HH; i += 256) qrow[i] = query[b * HH + i];
        __syncthreads();
        int wave = tid >> 6, lane = tid & 63;
        float4 q1 = *(const float4*)(qrow + lane * 8);
        float4 q2 = *(const float4*)(qrow + lane * 8 + 4);
        for (int i = wave; i < 128; i += 4) {
            int o = oq * 128 + i;
            const float4* w = (const float4*)(Wq + (size_t)o * HH);
            float4 a = w[lane * 2], c = w[lane * 2 + 1];
            float acc = a.x * q1.x + a.y * q1.y + a.z * q1.z + a.w * q1.w
                      + c.x * q2.x + c.y * q2.y + c.z * q2.z + c.w * q2.w;
            #pragma unroll
            for (int off = 1; off < 64; off <<= 1) acc += __shfl_xor(acc, off, 64);
            if (lane == 0) qb[b * HH + o] = acc + bias[o] + conv_b[o];
        }
    } else {
        for (int i = tid; i < BB; i += 256) ssum[i] = 0.f;
        for (int i = tid; i < BB * HH; i += 256) ctx[i] = 0.f;
    }
}

// ---------------- fused GEMM + conv + tanh + score + sigmoid + context ---------
// grid 512 = 16 b x 32 t-tiles; block 512 thr = 8 waves; 1 block/CU (128 KiB LDS).
// Block tile: 128 t x 512 o, K=512.  Wave ng: 128 rows x 32 cols (mt=8, nt=2).
// acc = 64 AGPR; B prefetch depth 2 via 4-slot register ring (32 VGPR).
// __launch_bounds__(512,2) -> 256-reg budget, no spill.
// As staged once (xor-swizzled, dynamic LDS); K-loop barrier-free; tile reused
// for the fused context reduction.
__global__ __launch_bounds__(512, 2) void gemm_fused_kernel(
        const float* __restrict__ value,
        const float* __restrict__ last_attn,
        const float* __restrict__ conv_w,
        const float* __restrict__ w_score,
        const float* __restrict__ b_score,
        const _Float16* __restrict__ Bpack,
        const float* __restrict__ qb,
        float* __restrict__ sbuf,
        float* __restrict__ ssum,
        float* __restrict__ ctx) {
    extern __shared__ _Float16 As[];    // 128 * 512 f16 = 128 KiB
    __shared__ float sred[128][8];
    __shared__ float s_lds[128];

    int tid = threadIdx.x;
    int blk = blockIdx.x;
    int b = blk >> 5;
    int t0 = (blk & 31) << 7;

    int lane = tid & 63, ng = tid >> 6;
    int quad = lane >> 4, lm = lane & 15;

    // B prologue: issue kb=0,1 before staging so they fly during the A stage
    const _Float16* bp = Bpack + (size_t)(ng * 2) * 512 + lane * 8;
    half8 breg[4][2];
    #pragma unroll
    for (int kb = 0; kb < 2; ++kb)
        #pragma unroll
        for (int nt = 0; nt < 2; ++nt)
            breg[kb][nt] = *(const half8*)(bp + kb * 16384 + nt * 512);
    bp += 2 * 16384;

    // ---- stage A: 128 rows x 512 f32 -> f16 LDS, xor-chunk swizzle ----
    {
        int st = tid >> 3, cc = tid & 7;
        #pragma unroll
        for (int r = 0; r < 2; ++r) {
            int row = st + r * 64;
            const float4* pA = (const float4*)(value + ((size_t)(b * TT + t0 + row)) * HH);
            #pragma unroll
            for (int u = 0; u < 8; ++u) {
                int c_log = cc + u * 8;
                float4 v0 = pA[2 * c_log], v1 = pA[2 * c_log + 1];
                int cph = c_log ^ (row & 7);
                half8 h = { (_Float16)v0.x, (_Float16)v0.y, (_Float16)v0.z, (_Float16)v0.w,
                            (_Float16)v1.x, (_Float16)v1.y, (_Float16)v1.z, (_Float16)v1.w };
                *(half8*)(As + row * 512 + cph * 8) = h;
            }
        }
    }

    f32x4 acc[8][2];
    #pragma unroll
    for (int mt = 0; mt < 8; ++mt)
        #pragma unroll
        for (int nt = 0; nt < 2; ++nt) { f32x4 z = {0.f,0.f,0.f,0.f}; acc[mt][nt] = z; }

    __syncthreads();

    #pragma unroll 4
    for (int kb = 0; kb < 16; ++kb) {
        if (kb < 14) {
            #pragma unroll
            for (int nt = 0; nt < 2; ++nt)
                breg[(kb + 2) & 3][nt] = *(const half8*)(bp + nt * 512);
            bp += 16384;
        }
        #pragma unroll
        for (int mt = 0; mt < 8; ++mt) {
            int tr = mt * 16 + lm;
            int cph = ((kb << 2) + quad) ^ (tr & 7);
            half8 a = *(const half8*)(As + tr * 512 + cph * 8);
            #pragma unroll
            for (int nt = 0; nt < 2; ++nt)
                acc[mt][nt] = __builtin_amdgcn_mfma_f32_16x16x32_f16(a, breg[kb & 3][nt], acc[mt][nt], 0, 0, 0);
        }
    }

    // ---- epilogue: conv + tanh + w_score dot ----
    float qvv[2], c0v[2], c1v[2], c2v[2], wvv[2];
    #pragma unroll
    for (int nt = 0; nt < 2; ++nt) {
        int o = ng * 32 + nt * 16 + lm;
        qvv[nt] = qb[b * HH + o];
        c0v[nt] = conv_w[o * 3 + 0];
        c1v[nt] = conv_w[o * 3 + 1];
        c2v[nt] = conv_w[o * 3 + 2];
        wvv[nt] = w_score[o];
    }
    #pragma unroll
    for (int mt = 0; mt < 8; ++mt) {
        float rsj[4];
        #pragma unroll
        for (int j = 0; j < 4; ++j) {
            int tg = t0 + mt * 16 + quad * 4 + j;
            const float* la = last_attn + b * TT + tg;
            float lam = (tg > 0) ? la[-1] : 0.f;
            float la0 = la[0];
            float lap = (tg < TT - 1) ? la[1] : 0.f;
            float r = 0.f;
            #pragma unroll
            for (int nt = 0; nt < 2; ++nt) {
                float act = acc[mt][nt][j] + qvv[nt]
                          + c0v[nt] * lam + c1v[nt] * la0 + c2v[nt] * lap;
                act = fminf(15.f, fmaxf(-15.f, act));
                float e2 = __expf(2.f * act);
                r += (1.f - 2.f * fast_rcp(e2 + 1.f)) * wvv[nt];
            }
            #pragma unroll
            for (int off = 1; off < 16; off <<= 1) r += __shfl_xor(r, off, 64);
            rsj[j] = r;
        }
        if (lm == 0)
            #pragma unroll
            for (int j = 0; j < 4; ++j)
                sred[mt * 16 + quad * 4 + j][ng] = rsj[j];
    }
    __syncthreads();

    if (tid < 128) {
        float sc = b_score[0];
        #pragma unroll
        for (int k = 0; k < 8; ++k) sc += sred[tid][k];
        float s = fast_rcp(1.f + __expf(-sc));
        s_lds[tid] = s;
        sbuf[b * TT + t0 + tid] = s;
        float tot = s;
        #pragma unroll
        for (int off = 1; off < 64; off <<= 1) tot += __shfl_xor(tot, off, 64);
        if ((tid & 63) == 0) atomicAdd(&ssum[b], tot);
    }
    __syncthreads();

    // ---- context partial from resident f16 tile: one column per thread ----
    {
        int h = tid;
        int cl = h >> 3, j = h & 7;
        float a = 0.f;
        #pragma unroll 8
        for (int t2 = 0; t2 < 128; ++t2) {
            int cph = cl ^ (t2 & 7);
            a += s_lds[t2] * (float)As[t2 * 512 + cph * 8 + j];
        }
        atomicAdd(&ctx[b * HH + h], a);
    }
}

// ---------------- finalize: out = [ctx/ssum, query] ++ attn = s/ssum -----------
__global__ void finalize_kernel(const float* __restrict__ query,
                                const float* __restrict__ ctx,
                                const float* __restrict__ sbuf,
                                const float* __restrict__ ssum,
                                float* __restrict__ out) {
    int idx = blockIdx.x * 256 + threadIdx.x;
    if (idx < BB * 2 * HH) {
        int b = idx >> 10, c = idx & 1023;
        float v;
        if (c < HH) v = ctx[b * HH + c] / ssum[b];
        else        v = query[b * HH + (c - HH)];
        out[idx] = v;
    } else {
        int j = idx - BB * 2 * HH;
        int b = j >> 12, t = j & 4095;
        out[idx] = sbuf[b * TT + t] / ssum[b];
    }
}

extern "C" void kernel_launch(void* const* d_in, const int* in_sizes, int n_in,
                              void* d_out, int out_size, void* d_ws, size_t ws_size,
                              hipStream_t stream) {
    const float* query     = (const float*)d_in[0];
    const float* value     = (const float*)d_in[1];
    const float* last_attn = (const float*)d_in[2];
    const float* conv_w    = (const float*)d_in[3];
    const float* conv_b    = (const float*)d_in[4];
    const float* Wq        = (const float*)d_in[5];
    const float* Wv        = (const float*)d_in[6];
    const float* bias      = (const float*)d_in[7];
    const float* w_score   = (const float*)d_in[8];
    const float* b_score   = (const float*)d_in[9];

    char* ws = (char*)d_ws;
    _Float16* Bpack = (_Float16*)ws;           // 524288 B
    float* qb     = (float*)(ws + 524288);     // 32768 B
    float* sbuf   = (float*)(ws + 557056);     // 262144 B
    float* ssum   = (float*)(ws + 819200);     // 64 B
    float* ctx    = (float*)(ws + 819264);     // 32768 B
    float* out    = (float*)d_out;

    static bool attr_set = false;
    if (!attr_set) {
        hipFuncSetAttribute((const void*)gemm_fused_kernel,
                            hipFuncAttributeMaxDynamicSharedMemorySize, 131072);
        attr_set = true;
    }

    prep_kernel<<<193, 256, 0, stream>>>(query, conv_b, Wq, Wv, bias, Bpack, qb, ssum, ctx);
    gemm_fused_kernel<<<512, 512, 131072, stream>>>(value, last_attn, conv_w, w_score,
                                                    b_score, Bpack, qb, sbuf, ssum, ctx);
    finalize_kernel<<<320, 256, 0, stream>>>(query, ctx, sbuf, ssum, out);
}